// Round 21
// baseline (223.855 us; speedup 1.0000x reference)
//
#include <hip/hip_runtime.h>
#include <hip/hip_bf16.h>

#define N_NODES 50000
#define N_EDGES 800000
#define DIM 128
#define NUM_REL 200
#define NREL2 (2 * NUM_REL)
#define NROWG (N_NODES / 16)      // 3125 row groups of 16 nodes
#define NBLK_G ((NROWG + 7) / 8)  // 391 gemm blocks (8 rgs each)
#define FILL_NB 633               // fill-only blocks: total grid = 1024 (full co-residency)
#define NCHUNK5 ((N_EDGES + 511) / 512)  // 1563 edge chunks of 512
#define NODES_PER_XCD (N_NODES / 8)  // 6250
#define CAP 64                    // bucket capacity (deg ~ Poisson(16))
// Zero-row padding: EEb row 100000 and Rb row 400 are all-zero.
#define ZROW (2 * N_NODES)
#define ZREL NREL2
#define ZPAY (ZROW | (ZREL << 17))

typedef __bf16 bf16x8 __attribute__((ext_vector_type(8)));
typedef float f32x4 __attribute__((ext_vector_type(4)));

// ---------------------------------------------------------------------------
// Dispatch 1: prep (WT hi/lo split, counts=0, pool=0, pad rows) U rel_tables.
// ---------------------------------------------------------------------------
__global__ void __launch_bounds__(256)
prep_rel_kernel(const float* __restrict__ rel_emb,
                const float* __restrict__ W_O_w, const float* __restrict__ W_O_b,
                const float* __restrict__ W_I_w, const float* __restrict__ W_I_b,
                const float* __restrict__ W_R_w, const float* __restrict__ W_R_b,
                const float* __restrict__ W_S_w,
                __bf16* __restrict__ WTh, __bf16* __restrict__ WTl,
                int* __restrict__ counts, int* __restrict__ pool,
                __bf16* __restrict__ EEb, __bf16* __restrict__ Rb,
                float* __restrict__ rel_new) {
    const int bid = blockIdx.x;
    if (bid < NREL2 / 2) {
        __shared__ float row[2][DIM];
        const int h = threadIdx.x >> 7;
        const int j = threadIdx.x & 127;
        const int t = bid * 2 + h;
        row[h][j] = rel_emb[t * DIM + j];
        __syncthreads();

        const bool fwd = (t < NUM_REL);
        const float* __restrict__ wSel = (fwd ? W_O_w : W_I_w) + j * (2 * DIM);
        const float* __restrict__ wR = W_R_w + j * DIM;
        float aSel = 0.f, aR = 0.f;
#pragma unroll 8
        for (int k = 0; k < DIM; ++k) {
            const float e = row[h][k];
            aSel += e * wSel[k];
            aR += e * wR[k];
        }
        Rb[t * DIM + j] = (__bf16)(aSel + (fwd ? W_O_b[j] : W_I_b[j]));
        rel_new[t * DIM + j] = aR + W_R_b[j];
    } else {
        const int idx = (bid - NREL2 / 2) * 256 + threadIdx.x;
        if (idx < 384 * DIM) {
            const int j = idx >> 7;
            const int k = idx & 127;
            float v;
            if (j < 128) v = W_O_w[j * (2 * DIM) + DIM + k];
            else if (j < 256) v = W_I_w[(j - 128) * (2 * DIM) + DIM + k];
            else v = W_S_w[(j - 256) * DIM + k];
            const __bf16 h = (__bf16)v;
            WTh[idx] = h;
            WTl[idx] = (__bf16)(v - (float)h);
        }
        if (idx < N_NODES) counts[idx] = 0;
        if (idx < 8) pool[idx] = 0;
        if (idx < DIM) {
            EEb[(size_t)ZROW * DIM + idx] = (__bf16)0.f;
            Rb[(size_t)ZREL * DIM + idx] = (__bf16)0.f;
        }
    }
}

// ---------------------------------------------------------------------------
// Dispatch 2: FUSED gemm + fill, 512-thread blocks, DYNAMIC fill pool.
// Grid = exactly 1024 blocks (4/CU co-residency, no dispatch tail).
// Blocks 0..390: 8-wave GEMM (one 32KB frag-packed B staging per cb serves
// 128 rows; 48 MFMAs/wave/cb; 0 bank conflicts), THEN join the fill pool.
// All blocks drain per-residue chunk pools (r = blockIdx&7 keeps the
// XCD-local write heuristic): gemm blocks convert their post-MFMA idle time
// into fill throughput, removing the round-20 fill tail where only 633
// blocks did all the scatter work.
// ---------------------------------------------------------------------------
#define REP4(F) F(0) F(1) F(2) F(3)

__global__ void __launch_bounds__(512, 1)
gemm_fill_kernel(const float* __restrict__ ent,
                 const __bf16* __restrict__ WTh, const __bf16* __restrict__ WTl,
                 const float* __restrict__ W_S_b,
                 __bf16* __restrict__ EEb, float* __restrict__ ent_S,
                 const int* __restrict__ src, const int* __restrict__ dst,
                 const int* __restrict__ et, int* __restrict__ counts,
                 int* __restrict__ sp, int* __restrict__ pool) {
    __shared__ __bf16 LBh[16 * 64 * 8];  // 16 KB
    __shared__ __bf16 LBl[16 * 64 * 8];  // 16 KB
    __shared__ int claim;

    if (blockIdx.x < NBLK_G) {
        // ================= GEMM role =================
        const int tid = threadIdx.x;
        const int wv = tid >> 6;              // 0..7
        const int rg = blockIdx.x * 8 + wv;
        const bool valid = (rg < NROWG);
        const int rgc = valid ? rg : (NROWG - 1);
        const int l = tid & 63;
        const int r16 = l & 15;
        const int kg = l >> 4;

        const float* __restrict__ aptr =
            ent + (size_t)(rgc * 16 + r16) * DIM + kg * 8;
#define ADECL(ks)                                                              \
        bf16x8 ah##ks, al##ks;                                                 \
        {                                                                      \
            const float4 v0 = *(const float4*)(aptr + (ks) * 32);              \
            const float4 v1 = *(const float4*)(aptr + (ks) * 32 + 4);          \
            const float xs[8] = {v0.x, v0.y, v0.z, v0.w, v1.x, v1.y, v1.z, v1.w}; \
            _Pragma("unroll") for (int i = 0; i < 8; ++i) {                    \
                const __bf16 h = (__bf16)xs[i];                                \
                ah##ks[i] = h;                                                 \
                al##ks[i] = (__bf16)(xs[i] - (float)h);                        \
            }                                                                  \
        }
        REP4(ADECL)
#undef ADECL

        const int orow = rgc * 16 + kg * 4;

#pragma unroll 1
        for (int cb = 0; cb < 6; ++cb) {
            __syncthreads();
#pragma unroll
            for (int i = 0; i < 2; ++i) {
                const int g = i * 512 + tid;     // 0..1023
                const int sks = g >> 6;          // 0..15
                const int ls = g & 63;
                const int s = sks >> 2;
                const int ks = sks & 3;
                const size_t soff = (size_t)(cb * 64 + s * 16 + (ls & 15)) * DIM
                                    + ks * 32 + (ls >> 4) * 8;
                *(bf16x8*)(&LBh[g * 8]) = *(const bf16x8*)(WTh + soff);
                *(bf16x8*)(&LBl[g * 8]) = *(const bf16x8*)(WTl + soff);
            }
            __syncthreads();

            f32x4 p0 = {0.f, 0.f, 0.f, 0.f}, q0 = {0.f, 0.f, 0.f, 0.f};
            f32x4 p1 = {0.f, 0.f, 0.f, 0.f}, q1 = {0.f, 0.f, 0.f, 0.f};
            f32x4 p2 = {0.f, 0.f, 0.f, 0.f}, q2 = {0.f, 0.f, 0.f, 0.f};
            f32x4 p3 = {0.f, 0.f, 0.f, 0.f}, q3 = {0.f, 0.f, 0.f, 0.f};

#define KS(ks)                                                                 \
    {                                                                          \
        const bf16x8 bh0 = *(const bf16x8*)(&LBh[((0 * 4 + (ks)) * 64 + l) * 8]); \
        const bf16x8 bh1 = *(const bf16x8*)(&LBh[((1 * 4 + (ks)) * 64 + l) * 8]); \
        const bf16x8 bh2 = *(const bf16x8*)(&LBh[((2 * 4 + (ks)) * 64 + l) * 8]); \
        const bf16x8 bh3 = *(const bf16x8*)(&LBh[((3 * 4 + (ks)) * 64 + l) * 8]); \
        const bf16x8 bl0 = *(const bf16x8*)(&LBl[((0 * 4 + (ks)) * 64 + l) * 8]); \
        const bf16x8 bl1 = *(const bf16x8*)(&LBl[((1 * 4 + (ks)) * 64 + l) * 8]); \
        const bf16x8 bl2 = *(const bf16x8*)(&LBl[((2 * 4 + (ks)) * 64 + l) * 8]); \
        const bf16x8 bl3 = *(const bf16x8*)(&LBl[((3 * 4 + (ks)) * 64 + l) * 8]); \
        p0 = __builtin_amdgcn_mfma_f32_16x16x32_bf16(ah##ks, bh0, p0, 0, 0, 0); \
        p1 = __builtin_amdgcn_mfma_f32_16x16x32_bf16(ah##ks, bh1, p1, 0, 0, 0); \
        p2 = __builtin_amdgcn_mfma_f32_16x16x32_bf16(ah##ks, bh2, p2, 0, 0, 0); \
        p3 = __builtin_amdgcn_mfma_f32_16x16x32_bf16(ah##ks, bh3, p3, 0, 0, 0); \
        q0 = __builtin_amdgcn_mfma_f32_16x16x32_bf16(al##ks, bh0, q0, 0, 0, 0); \
        q1 = __builtin_amdgcn_mfma_f32_16x16x32_bf16(al##ks, bh1, q1, 0, 0, 0); \
        q2 = __builtin_amdgcn_mfma_f32_16x16x32_bf16(al##ks, bh2, q2, 0, 0, 0); \
        q3 = __builtin_amdgcn_mfma_f32_16x16x32_bf16(al##ks, bh3, q3, 0, 0, 0); \
        q0 = __builtin_amdgcn_mfma_f32_16x16x32_bf16(ah##ks, bl0, q0, 0, 0, 0); \
        q1 = __builtin_amdgcn_mfma_f32_16x16x32_bf16(ah##ks, bl1, q1, 0, 0, 0); \
        q2 = __builtin_amdgcn_mfma_f32_16x16x32_bf16(ah##ks, bl2, q2, 0, 0, 0); \
        q3 = __builtin_amdgcn_mfma_f32_16x16x32_bf16(ah##ks, bl3, q3, 0, 0, 0); \
    }
            REP4(KS)
#undef KS

            if (valid) {
                const int colb = (cb & 1) * 64;
                if (cb < 4) {
                    __bf16* __restrict__ obb =
                        EEb + ((cb < 2) ? 0 : (size_t)N_NODES * DIM);
#define ST(s, P, Q)                                                            \
                    {                                                          \
                        const int col = colb + (s) * 16 + r16;                 \
                        const f32x4 a = P + Q;                                 \
                        obb[(size_t)(orow + 0) * DIM + col] = (__bf16)a[0];    \
                        obb[(size_t)(orow + 1) * DIM + col] = (__bf16)a[1];    \
                        obb[(size_t)(orow + 2) * DIM + col] = (__bf16)a[2];    \
                        obb[(size_t)(orow + 3) * DIM + col] = (__bf16)a[3];    \
                    }
                    ST(0, p0, q0) ST(1, p1, q1) ST(2, p2, q2) ST(3, p3, q3)
#undef ST
                } else {
#define ST(s, P, Q)                                                            \
                    {                                                          \
                        const int col = colb + (s) * 16 + r16;                 \
                        const float bs = W_S_b[col];                           \
                        const f32x4 a = P + Q;                                 \
                        ent_S[(size_t)(orow + 0) * DIM + col] = a[0] + bs;     \
                        ent_S[(size_t)(orow + 1) * DIM + col] = a[1] + bs;     \
                        ent_S[(size_t)(orow + 2) * DIM + col] = a[2] + bs;     \
                        ent_S[(size_t)(orow + 3) * DIM + col] = a[3] + bs;     \
                    }
                    ST(0, p0, q0) ST(1, p1, q1) ST(2, p2, q2) ST(3, p3, q3)
#undef ST
                }
            }
        }
    }

    // ================= FILL pool drain (ALL blocks) =================
    const int r = blockIdx.x & 7;  // XCD heuristic (round-robin dispatch)
    const int rlo = r * NODES_PER_XCD;
    for (;;) {
        __syncthreads();
        if (threadIdx.x == 0) claim = atomicAdd(&pool[r], 1);
        __syncthreads();
        const int c = claim;
        if (c >= NCHUNK5) break;
        const int e = c * 512 + threadIdx.x;
        if (e < N_EDGES) {
            const int d = dst[e];
            if ((unsigned)(d - rlo) < (unsigned)NODES_PER_XCD) {
                const int t = et[e];
                const int row = src[e] + ((t < NUM_REL) ? 0 : N_NODES);
                const int pos = atomicAdd(&counts[d], 1);
                if (pos < CAP) sp[(d << 6) + pos] = row | (t << 17);
            }
        }
    }
}

// ---------------------------------------------------------------------------
// Dispatch 3: gather-reduce (unchanged).
// ---------------------------------------------------------------------------
__global__ void __launch_bounds__(256)
gather_kernel(const int* __restrict__ counts, const int* __restrict__ sp,
              const __bf16* __restrict__ EEb, const __bf16* __restrict__ Rb,
              const float* __restrict__ ent_S, float* __restrict__ out_ent) {
    const int node = blockIdx.x * 4 + (threadIdx.x >> 6);
    if (node >= N_NODES) return;
    const int l = threadIdx.x & 63;
    const int q = l >> 4;
    const int m = l & 15;

    const int cntT = counts[node];
    const int cnt = min(cntT, CAP);

    float a0 = 0.f, a1 = 0.f, a2 = 0.f, a3 = 0.f;
    float a4 = 0.f, a5 = 0.f, a6 = 0.f, a7 = 0.f;
    const char* __restrict__ Eb = (const char*)EEb + 16 * m;
    const char* __restrict__ Rp = (const char*)Rb + 16 * m;

    const int myp = (l < cnt) ? sp[(node << 6) + l] : ZPAY;
#pragma unroll 2
    for (int i = 0; i < cnt; i += 4) {
        const int p = __shfl(myp, i + q);
        const unsigned eoff = (unsigned)(p & 0x1FFFF) << 8;
        const unsigned roff = ((unsigned)p >> 17) << 8;
        const uint4 ev = *(const uint4*)(Eb + eoff);
        const uint4 rv = *(const uint4*)(Rp + roff);
        a0 += __uint_as_float(ev.x << 16) + __uint_as_float(rv.x << 16);
        a1 += __uint_as_float(ev.x & 0xffff0000u) +
              __uint_as_float(rv.x & 0xffff0000u);
        a2 += __uint_as_float(ev.y << 16) + __uint_as_float(rv.y << 16);
        a3 += __uint_as_float(ev.y & 0xffff0000u) +
              __uint_as_float(rv.y & 0xffff0000u);
        a4 += __uint_as_float(ev.z << 16) + __uint_as_float(rv.z << 16);
        a5 += __uint_as_float(ev.z & 0xffff0000u) +
              __uint_as_float(rv.z & 0xffff0000u);
        a6 += __uint_as_float(ev.w << 16) + __uint_as_float(rv.w << 16);
        a7 += __uint_as_float(ev.w & 0xffff0000u) +
              __uint_as_float(rv.w & 0xffff0000u);
    }

#define RED(A) A += __shfl_xor(A, 16); A += __shfl_xor(A, 32);
    RED(a0) RED(a1) RED(a2) RED(a3) RED(a4) RED(a5) RED(a6) RED(a7)
#undef RED

    if (l < 16) {
        const float inv = 1.0f / fmaxf((float)cntT, 1.0f);
        const float* sp_ = ent_S + (size_t)node * DIM + 8 * m;
        const float4 s0 = *(const float4*)(sp_);
        const float4 s1 = *(const float4*)(sp_ + 4);
        float4 o0, o1;
        o0.x = s0.x + a0 * inv;
        o0.y = s0.y + a1 * inv;
        o0.z = s0.z + a2 * inv;
        o0.w = s0.w + a3 * inv;
        o1.x = s1.x + a4 * inv;
        o1.y = s1.y + a5 * inv;
        o1.z = s1.z + a6 * inv;
        o1.w = s1.w + a7 * inv;
        float* op = out_ent + (size_t)node * DIM + 8 * m;
        *(float4*)(op) = o0;
        *(float4*)(op + 4) = o1;
    }
}

extern "C" void kernel_launch(void* const* d_in, const int* in_sizes, int n_in,
                              void* d_out, int out_size, void* d_ws, size_t ws_size,
                              hipStream_t stream) {
    const int* src = (const int*)d_in[0];
    const int* dst = (const int*)d_in[1];
    const int* et = (const int*)d_in[2];
    const float* ent_emb = (const float*)d_in[3];
    const float* rel_emb = (const float*)d_in[4];
    const float* W_O_w = (const float*)d_in[5];
    const float* W_O_b = (const float*)d_in[6];
    const float* W_I_w = (const float*)d_in[7];
    const float* W_I_b = (const float*)d_in[8];
    const float* W_S_w = (const float*)d_in[9];
    const float* W_S_b = (const float*)d_in[10];
    const float* W_R_w = (const float*)d_in[11];
    const float* W_R_b = (const float*)d_in[12];

    float* out_ent = (float*)d_out;                    // [50000*128]
    float* out_rel = out_ent + (size_t)N_NODES * DIM;  // [400*128]

    // Workspace layout (floats):
    // ent_S | EEb(bf16, 100001 rows) | Rb(bf16, 401 rows) | WTh | WTl |
    // counts(50000 int) | pool(8 int) | sp(50000*64 int)
    float* wsf = (float*)d_ws;
    float* ent_S = wsf;
    wsf += (size_t)N_NODES * DIM;
    __bf16* EEb = (__bf16*)wsf;
    wsf += ((size_t)(2 * N_NODES + 1) * DIM + 1) / 2;
    __bf16* Rb = (__bf16*)wsf;
    wsf += (size_t)(NREL2 + 1) * DIM / 2;
    __bf16* WTh = (__bf16*)wsf;
    wsf += 384 * DIM / 2;
    __bf16* WTl = (__bf16*)wsf;
    wsf += 384 * DIM / 2;
    int* counts = (int*)wsf;
    int* pool = counts + N_NODES;
    int* sp = pool + 8;
    // total ~65 MB

    prep_rel_kernel<<<NREL2 / 2 + 196, 256, 0, stream>>>(
        rel_emb, W_O_w, W_O_b, W_I_w, W_I_b, W_R_w, W_R_b, W_S_w,
        WTh, WTl, counts, pool, EEb, Rb, out_rel);

    gemm_fill_kernel<<<NBLK_G + FILL_NB, 512, 0, stream>>>(
        ent_emb, WTh, WTl, W_S_b, EEb, ent_S, src, dst, et, counts, sp, pool);

    gather_kernel<<<(N_NODES + 3) / 4, 256, 0, stream>>>(counts, sp, EEb, Rb,
                                                         ent_S, out_ent);
}

// Round 22
// 113.965 us; speedup vs baseline: 1.9642x; 1.9642x over previous
//
#include <hip/hip_runtime.h>
#include <hip/hip_bf16.h>

#define N_NODES 50000
#define N_EDGES 800000
#define DIM 128
#define NUM_REL 200
#define NREL2 (2 * NUM_REL)
#define NROWG (N_NODES / 16)      // 3125 row groups of 16 nodes
#define NBLK_G ((NROWG + 7) / 8)  // 391 gemm blocks (8 rgs each)
#define GRID_NB 1024              // total blocks: full 4/CU co-residency
#define NCHUNK5 ((N_EDGES + 511) / 512)  // 1563 edge chunks of 512
#define C1 1360                   // chunk split: [0,C1) fill-only, [C1,..) gemm
#define NODES_PER_XCD (N_NODES / 8)  // 6250
#define CAP 64                    // bucket capacity (deg ~ Poisson(16))
// Zero-row padding: EEb row 100000 and Rb row 400 are all-zero.
#define ZROW (2 * N_NODES)
#define ZREL NREL2
#define ZPAY (ZROW | (ZREL << 17))

typedef __bf16 bf16x8 __attribute__((ext_vector_type(8)));
typedef float f32x4 __attribute__((ext_vector_type(4)));

// ---------------------------------------------------------------------------
// Dispatch 1: prep (WT hi/lo split, counts=0, pad rows) U rel_tables.
// ---------------------------------------------------------------------------
__global__ void __launch_bounds__(256)
prep_rel_kernel(const float* __restrict__ rel_emb,
                const float* __restrict__ W_O_w, const float* __restrict__ W_O_b,
                const float* __restrict__ W_I_w, const float* __restrict__ W_I_b,
                const float* __restrict__ W_R_w, const float* __restrict__ W_R_b,
                const float* __restrict__ W_S_w,
                __bf16* __restrict__ WTh, __bf16* __restrict__ WTl,
                int* __restrict__ counts, __bf16* __restrict__ EEb,
                __bf16* __restrict__ Rb, float* __restrict__ rel_new) {
    const int bid = blockIdx.x;
    if (bid < NREL2 / 2) {
        __shared__ float row[2][DIM];
        const int h = threadIdx.x >> 7;
        const int j = threadIdx.x & 127;
        const int t = bid * 2 + h;
        row[h][j] = rel_emb[t * DIM + j];
        __syncthreads();

        const bool fwd = (t < NUM_REL);
        const float* __restrict__ wSel = (fwd ? W_O_w : W_I_w) + j * (2 * DIM);
        const float* __restrict__ wR = W_R_w + j * DIM;
        float aSel = 0.f, aR = 0.f;
#pragma unroll 8
        for (int k = 0; k < DIM; ++k) {
            const float e = row[h][k];
            aSel += e * wSel[k];
            aR += e * wR[k];
        }
        Rb[t * DIM + j] = (__bf16)(aSel + (fwd ? W_O_b[j] : W_I_b[j]));
        rel_new[t * DIM + j] = aR + W_R_b[j];
    } else {
        const int idx = (bid - NREL2 / 2) * 256 + threadIdx.x;
        if (idx < 384 * DIM) {
            const int j = idx >> 7;
            const int k = idx & 127;
            float v;
            if (j < 128) v = W_O_w[j * (2 * DIM) + DIM + k];
            else if (j < 256) v = W_I_w[(j - 128) * (2 * DIM) + DIM + k];
            else v = W_S_w[(j - 256) * DIM + k];
            const __bf16 h = (__bf16)v;
            WTh[idx] = h;
            WTl[idx] = (__bf16)(v - (float)h);
        }
        if (idx < N_NODES) counts[idx] = 0;
        if (idx < DIM) {
            EEb[(size_t)ZROW * DIM + idx] = (__bf16)0.f;
            Rb[(size_t)ZREL * DIM + idx] = (__bf16)0.f;
        }
    }
}

// ---------------------------------------------------------------------------
// Dispatch 2: FUSED gemm + fill, 512-thread blocks, STATIC load balance.
// Grid = exactly 1024 blocks.  Residue r = blockIdx&7 (XCD-local writes),
// local index j = blockIdx>>3.  Per residue: g_r = (398-r)/8 gemm blocks,
// f_r = 128-g_r fill-only.  Chunks [0,C1) -> fill-only (stride f_r);
// [C1,NCHUNK5) -> gemm blocks AFTER their 6 MFMA iterations (stride g_r).
// Every (chunk,residue) pair exactly once; no atomics/barriers for the
// assignment (round-21's dynamic pool convoyed on one cache line).
// GEMM role: v20-proven 8-wave, one 32KB frag-packed B staging per cb.
// ---------------------------------------------------------------------------
#define REP4(F) F(0) F(1) F(2) F(3)

__global__ void __launch_bounds__(512, 1)
gemm_fill_kernel(const float* __restrict__ ent,
                 const __bf16* __restrict__ WTh, const __bf16* __restrict__ WTl,
                 const float* __restrict__ W_S_b,
                 __bf16* __restrict__ EEb, float* __restrict__ ent_S,
                 const int* __restrict__ src, const int* __restrict__ dst,
                 const int* __restrict__ et, int* __restrict__ counts,
                 int* __restrict__ sp) {
    __shared__ __bf16 LBh[16 * 64 * 8];  // 16 KB
    __shared__ __bf16 LBl[16 * 64 * 8];  // 16 KB

    const int r = blockIdx.x & 7;        // residue / XCD heuristic
    const int j = blockIdx.x >> 3;       // local index within residue
    const int g_r = (398 - r) / 8;       // gemm blocks in this residue
    const int rlo = r * NODES_PER_XCD;

#define FILL_CHUNK(c)                                                          \
    {                                                                          \
        const int e = (c) * 512 + (int)threadIdx.x;                            \
        if (e < N_EDGES) {                                                     \
            const int d = dst[e];                                              \
            if ((unsigned)(d - rlo) < (unsigned)NODES_PER_XCD) {               \
                const int t = et[e];                                           \
                const int row = src[e] + ((t < NUM_REL) ? 0 : N_NODES);        \
                const int pos = atomicAdd(&counts[d], 1);                      \
                if (pos < CAP) sp[(d << 6) + pos] = row | (t << 17);           \
            }                                                                  \
        }                                                                      \
    }

    if (blockIdx.x >= NBLK_G) {
        // ================= FILL-ONLY role: chunks [0, C1) =================
        const int f_r = 128 - g_r;
        const int jf = j - g_r;
#pragma unroll 1
        for (int c = jf; c < C1; c += f_r) FILL_CHUNK(c)
        return;
    }

    // ================= GEMM role =================
    {
        const int tid = threadIdx.x;
        const int wv = tid >> 6;              // 0..7
        const int rg = blockIdx.x * 8 + wv;
        const bool valid = (rg < NROWG);
        const int rgc = valid ? rg : (NROWG - 1);
        const int l = tid & 63;
        const int r16 = l & 15;
        const int kg = l >> 4;

        const float* __restrict__ aptr =
            ent + (size_t)(rgc * 16 + r16) * DIM + kg * 8;
#define ADECL(ks)                                                              \
        bf16x8 ah##ks, al##ks;                                                 \
        {                                                                      \
            const float4 v0 = *(const float4*)(aptr + (ks) * 32);              \
            const float4 v1 = *(const float4*)(aptr + (ks) * 32 + 4);          \
            const float xs[8] = {v0.x, v0.y, v0.z, v0.w, v1.x, v1.y, v1.z, v1.w}; \
            _Pragma("unroll") for (int i = 0; i < 8; ++i) {                    \
                const __bf16 h = (__bf16)xs[i];                                \
                ah##ks[i] = h;                                                 \
                al##ks[i] = (__bf16)(xs[i] - (float)h);                        \
            }                                                                  \
        }
        REP4(ADECL)
#undef ADECL

        const int orow = rgc * 16 + kg * 4;

#pragma unroll 1
        for (int cb = 0; cb < 6; ++cb) {
            __syncthreads();
#pragma unroll
            for (int i = 0; i < 2; ++i) {
                const int g = i * 512 + tid;     // 0..1023
                const int sks = g >> 6;          // 0..15
                const int ls = g & 63;
                const int s = sks >> 2;
                const int ks = sks & 3;
                const size_t soff = (size_t)(cb * 64 + s * 16 + (ls & 15)) * DIM
                                    + ks * 32 + (ls >> 4) * 8;
                *(bf16x8*)(&LBh[g * 8]) = *(const bf16x8*)(WTh + soff);
                *(bf16x8*)(&LBl[g * 8]) = *(const bf16x8*)(WTl + soff);
            }
            __syncthreads();

            f32x4 p0 = {0.f, 0.f, 0.f, 0.f}, q0 = {0.f, 0.f, 0.f, 0.f};
            f32x4 p1 = {0.f, 0.f, 0.f, 0.f}, q1 = {0.f, 0.f, 0.f, 0.f};
            f32x4 p2 = {0.f, 0.f, 0.f, 0.f}, q2 = {0.f, 0.f, 0.f, 0.f};
            f32x4 p3 = {0.f, 0.f, 0.f, 0.f}, q3 = {0.f, 0.f, 0.f, 0.f};

#define KS(ks)                                                                 \
    {                                                                          \
        const bf16x8 bh0 = *(const bf16x8*)(&LBh[((0 * 4 + (ks)) * 64 + l) * 8]); \
        const bf16x8 bh1 = *(const bf16x8*)(&LBh[((1 * 4 + (ks)) * 64 + l) * 8]); \
        const bf16x8 bh2 = *(const bf16x8*)(&LBh[((2 * 4 + (ks)) * 64 + l) * 8]); \
        const bf16x8 bh3 = *(const bf16x8*)(&LBh[((3 * 4 + (ks)) * 64 + l) * 8]); \
        const bf16x8 bl0 = *(const bf16x8*)(&LBl[((0 * 4 + (ks)) * 64 + l) * 8]); \
        const bf16x8 bl1 = *(const bf16x8*)(&LBl[((1 * 4 + (ks)) * 64 + l) * 8]); \
        const bf16x8 bl2 = *(const bf16x8*)(&LBl[((2 * 4 + (ks)) * 64 + l) * 8]); \
        const bf16x8 bl3 = *(const bf16x8*)(&LBl[((3 * 4 + (ks)) * 64 + l) * 8]); \
        p0 = __builtin_amdgcn_mfma_f32_16x16x32_bf16(ah##ks, bh0, p0, 0, 0, 0); \
        p1 = __builtin_amdgcn_mfma_f32_16x16x32_bf16(ah##ks, bh1, p1, 0, 0, 0); \
        p2 = __builtin_amdgcn_mfma_f32_16x16x32_bf16(ah##ks, bh2, p2, 0, 0, 0); \
        p3 = __builtin_amdgcn_mfma_f32_16x16x32_bf16(ah##ks, bh3, p3, 0, 0, 0); \
        q0 = __builtin_amdgcn_mfma_f32_16x16x32_bf16(al##ks, bh0, q0, 0, 0, 0); \
        q1 = __builtin_amdgcn_mfma_f32_16x16x32_bf16(al##ks, bh1, q1, 0, 0, 0); \
        q2 = __builtin_amdgcn_mfma_f32_16x16x32_bf16(al##ks, bh2, q2, 0, 0, 0); \
        q3 = __builtin_amdgcn_mfma_f32_16x16x32_bf16(al##ks, bh3, q3, 0, 0, 0); \
        q0 = __builtin_amdgcn_mfma_f32_16x16x32_bf16(ah##ks, bl0, q0, 0, 0, 0); \
        q1 = __builtin_amdgcn_mfma_f32_16x16x32_bf16(ah##ks, bl1, q1, 0, 0, 0); \
        q2 = __builtin_amdgcn_mfma_f32_16x16x32_bf16(ah##ks, bl2, q2, 0, 0, 0); \
        q3 = __builtin_amdgcn_mfma_f32_16x16x32_bf16(ah##ks, bl3, q3, 0, 0, 0); \
    }
            REP4(KS)
#undef KS

            if (valid) {
                const int colb = (cb & 1) * 64;
                if (cb < 4) {
                    __bf16* __restrict__ obb =
                        EEb + ((cb < 2) ? 0 : (size_t)N_NODES * DIM);
#define ST(s, P, Q)                                                            \
                    {                                                          \
                        const int col = colb + (s) * 16 + r16;                 \
                        const f32x4 a = P + Q;                                 \
                        obb[(size_t)(orow + 0) * DIM + col] = (__bf16)a[0];    \
                        obb[(size_t)(orow + 1) * DIM + col] = (__bf16)a[1];    \
                        obb[(size_t)(orow + 2) * DIM + col] = (__bf16)a[2];    \
                        obb[(size_t)(orow + 3) * DIM + col] = (__bf16)a[3];    \
                    }
                    ST(0, p0, q0) ST(1, p1, q1) ST(2, p2, q2) ST(3, p3, q3)
#undef ST
                } else {
#define ST(s, P, Q)                                                            \
                    {                                                          \
                        const int col = colb + (s) * 16 + r16;                 \
                        const float bs = W_S_b[col];                           \
                        const f32x4 a = P + Q;                                 \
                        ent_S[(size_t)(orow + 0) * DIM + col] = a[0] + bs;     \
                        ent_S[(size_t)(orow + 1) * DIM + col] = a[1] + bs;     \
                        ent_S[(size_t)(orow + 2) * DIM + col] = a[2] + bs;     \
                        ent_S[(size_t)(orow + 3) * DIM + col] = a[3] + bs;     \
                    }
                    ST(0, p0, q0) ST(1, p1, q1) ST(2, p2, q2) ST(3, p3, q3)
#undef ST
                }
            }
        }
    }

    // ---- GEMM blocks' static fill share: chunks [C1, NCHUNK5), stride g_r.
#pragma unroll 1
    for (int c = C1 + j; c < NCHUNK5; c += g_r) FILL_CHUNK(c)
#undef FILL_CHUNK
}

// ---------------------------------------------------------------------------
// Dispatch 3: gather-reduce (unchanged).
// ---------------------------------------------------------------------------
__global__ void __launch_bounds__(256)
gather_kernel(const int* __restrict__ counts, const int* __restrict__ sp,
              const __bf16* __restrict__ EEb, const __bf16* __restrict__ Rb,
              const float* __restrict__ ent_S, float* __restrict__ out_ent) {
    const int node = blockIdx.x * 4 + (threadIdx.x >> 6);
    if (node >= N_NODES) return;
    const int l = threadIdx.x & 63;
    const int q = l >> 4;
    const int m = l & 15;

    const int cntT = counts[node];
    const int cnt = min(cntT, CAP);

    float a0 = 0.f, a1 = 0.f, a2 = 0.f, a3 = 0.f;
    float a4 = 0.f, a5 = 0.f, a6 = 0.f, a7 = 0.f;
    const char* __restrict__ Eb = (const char*)EEb + 16 * m;
    const char* __restrict__ Rp = (const char*)Rb + 16 * m;

    const int myp = (l < cnt) ? sp[(node << 6) + l] : ZPAY;
#pragma unroll 2
    for (int i = 0; i < cnt; i += 4) {
        const int p = __shfl(myp, i + q);
        const unsigned eoff = (unsigned)(p & 0x1FFFF) << 8;
        const unsigned roff = ((unsigned)p >> 17) << 8;
        const uint4 ev = *(const uint4*)(Eb + eoff);
        const uint4 rv = *(const uint4*)(Rp + roff);
        a0 += __uint_as_float(ev.x << 16) + __uint_as_float(rv.x << 16);
        a1 += __uint_as_float(ev.x & 0xffff0000u) +
              __uint_as_float(rv.x & 0xffff0000u);
        a2 += __uint_as_float(ev.y << 16) + __uint_as_float(rv.y << 16);
        a3 += __uint_as_float(ev.y & 0xffff0000u) +
              __uint_as_float(rv.y & 0xffff0000u);
        a4 += __uint_as_float(ev.z << 16) + __uint_as_float(rv.z << 16);
        a5 += __uint_as_float(ev.z & 0xffff0000u) +
              __uint_as_float(rv.z & 0xffff0000u);
        a6 += __uint_as_float(ev.w << 16) + __uint_as_float(rv.w << 16);
        a7 += __uint_as_float(ev.w & 0xffff0000u) +
              __uint_as_float(rv.w & 0xffff0000u);
    }

#define RED(A) A += __shfl_xor(A, 16); A += __shfl_xor(A, 32);
    RED(a0) RED(a1) RED(a2) RED(a3) RED(a4) RED(a5) RED(a6) RED(a7)
#undef RED

    if (l < 16) {
        const float inv = 1.0f / fmaxf((float)cntT, 1.0f);
        const float* sp_ = ent_S + (size_t)node * DIM + 8 * m;
        const float4 s0 = *(const float4*)(sp_);
        const float4 s1 = *(const float4*)(sp_ + 4);
        float4 o0, o1;
        o0.x = s0.x + a0 * inv;
        o0.y = s0.y + a1 * inv;
        o0.z = s0.z + a2 * inv;
        o0.w = s0.w + a3 * inv;
        o1.x = s1.x + a4 * inv;
        o1.y = s1.y + a5 * inv;
        o1.z = s1.z + a6 * inv;
        o1.w = s1.w + a7 * inv;
        float* op = out_ent + (size_t)node * DIM + 8 * m;
        *(float4*)(op) = o0;
        *(float4*)(op + 4) = o1;
    }
}

extern "C" void kernel_launch(void* const* d_in, const int* in_sizes, int n_in,
                              void* d_out, int out_size, void* d_ws, size_t ws_size,
                              hipStream_t stream) {
    const int* src = (const int*)d_in[0];
    const int* dst = (const int*)d_in[1];
    const int* et = (const int*)d_in[2];
    const float* ent_emb = (const float*)d_in[3];
    const float* rel_emb = (const float*)d_in[4];
    const float* W_O_w = (const float*)d_in[5];
    const float* W_O_b = (const float*)d_in[6];
    const float* W_I_w = (const float*)d_in[7];
    const float* W_I_b = (const float*)d_in[8];
    const float* W_S_w = (const float*)d_in[9];
    const float* W_S_b = (const float*)d_in[10];
    const float* W_R_w = (const float*)d_in[11];
    const float* W_R_b = (const float*)d_in[12];

    float* out_ent = (float*)d_out;                    // [50000*128]
    float* out_rel = out_ent + (size_t)N_NODES * DIM;  // [400*128]

    // Workspace layout (floats):
    // ent_S | EEb(bf16, 100001 rows) | Rb(bf16, 401 rows) | WTh | WTl |
    // counts(50000 int) | sp(50000*64 int)
    float* wsf = (float*)d_ws;
    float* ent_S = wsf;
    wsf += (size_t)N_NODES * DIM;
    __bf16* EEb = (__bf16*)wsf;
    wsf += ((size_t)(2 * N_NODES + 1) * DIM + 1) / 2;
    __bf16* Rb = (__bf16*)wsf;
    wsf += (size_t)(NREL2 + 1) * DIM / 2;
    __bf16* WTh = (__bf16*)wsf;
    wsf += 384 * DIM / 2;
    __bf16* WTl = (__bf16*)wsf;
    wsf += 384 * DIM / 2;
    int* counts = (int*)wsf;
    int* sp = counts + N_NODES;
    // total ~65 MB

    prep_rel_kernel<<<NREL2 / 2 + 196, 256, 0, stream>>>(
        rel_emb, W_O_w, W_O_b, W_I_w, W_I_b, W_R_w, W_R_b, W_S_w,
        WTh, WTl, counts, EEb, Rb, out_rel);

    gemm_fill_kernel<<<GRID_NB, 512, 0, stream>>>(
        ent_emb, WTh, WTl, W_S_b, EEb, ent_S, src, dst, et, counts, sp);

    gather_kernel<<<(N_NODES + 3) / 4, 256, 0, stream>>>(counts, sp, EEb, Rb,
                                                         ent_S, out_ent);
}

// Round 23
// 110.067 us; speedup vs baseline: 2.0338x; 1.0354x over previous
//
#include <hip/hip_runtime.h>
#include <hip/hip_bf16.h>

#define N_NODES 50000
#define N_EDGES 800000
#define DIM 128
#define NUM_REL 200
#define NREL2 (2 * NUM_REL)
#define NROWG (N_NODES / 16)      // 3125 row groups of 16 nodes
#define NBLK_G ((NROWG + 7) / 8)  // 391 gemm blocks (8 rgs each)
#define FILL_NB 1024              // fill blocks (multiple of 8)
#define NCHUNK5 ((N_EDGES + 511) / 512)  // 1563 edge chunks of 512
#define NODES_PER_XCD (N_NODES / 8)  // 6250
#define CAP 64                    // bucket capacity (deg ~ Poisson(16))
// Zero-row padding: EEb row 100000 and Rb row 400 are all-zero.
#define ZROW (2 * N_NODES)
#define ZREL NREL2
#define ZPAY (ZROW | (ZREL << 17))

typedef __bf16 bf16x8 __attribute__((ext_vector_type(8)));
typedef float f32x4 __attribute__((ext_vector_type(4)));

// ---------------------------------------------------------------------------
// Dispatch 1: prep (WT hi/lo split, counts=0, pad rows) U rel_tables.
// ---------------------------------------------------------------------------
__global__ void __launch_bounds__(256)
prep_rel_kernel(const float* __restrict__ rel_emb,
                const float* __restrict__ W_O_w, const float* __restrict__ W_O_b,
                const float* __restrict__ W_I_w, const float* __restrict__ W_I_b,
                const float* __restrict__ W_R_w, const float* __restrict__ W_R_b,
                const float* __restrict__ W_S_w,
                __bf16* __restrict__ WTh, __bf16* __restrict__ WTl,
                int* __restrict__ counts, __bf16* __restrict__ EEb,
                __bf16* __restrict__ Rb, float* __restrict__ rel_new) {
    const int bid = blockIdx.x;
    if (bid < NREL2 / 2) {
        __shared__ float row[2][DIM];
        const int h = threadIdx.x >> 7;
        const int j = threadIdx.x & 127;
        const int t = bid * 2 + h;
        row[h][j] = rel_emb[t * DIM + j];
        __syncthreads();

        const bool fwd = (t < NUM_REL);
        const float* __restrict__ wSel = (fwd ? W_O_w : W_I_w) + j * (2 * DIM);
        const float* __restrict__ wR = W_R_w + j * DIM;
        float aSel = 0.f, aR = 0.f;
#pragma unroll 8
        for (int k = 0; k < DIM; ++k) {
            const float e = row[h][k];
            aSel += e * wSel[k];
            aR += e * wR[k];
        }
        Rb[t * DIM + j] = (__bf16)(aSel + (fwd ? W_O_b[j] : W_I_b[j]));
        rel_new[t * DIM + j] = aR + W_R_b[j];
    } else {
        const int idx = (bid - NREL2 / 2) * 256 + threadIdx.x;
        if (idx < 384 * DIM) {
            const int j = idx >> 7;
            const int k = idx & 127;
            float v;
            if (j < 128) v = W_O_w[j * (2 * DIM) + DIM + k];
            else if (j < 256) v = W_I_w[(j - 128) * (2 * DIM) + DIM + k];
            else v = W_S_w[(j - 256) * DIM + k];
            const __bf16 h = (__bf16)v;
            WTh[idx] = h;
            WTl[idx] = (__bf16)(v - (float)h);
        }
        if (idx < N_NODES) counts[idx] = 0;
        if (idx < DIM) {
            EEb[(size_t)ZROW * DIM + idx] = (__bf16)0.f;
            Rb[(size_t)ZREL * DIM + idx] = (__bf16)0.f;
        }
    }
}

// ---------------------------------------------------------------------------
// Dispatch 2: FUSED gemm + fill (v20 structure — best measured — plus
// unroll-2 fill chains).  512-thread blocks; grid 391 gemm + 1024 fill.
// GEMM: 8 waves x 1 rg, one 32KB frag-packed B staging per cb (0 conflicts).
// FILL: XCD-partitioned bucket scatter; each loop iteration now processes
// chunks c and c+128 back-to-back -> two INDEPENDENT load->atomic->store
// chains in flight per thread (the previous unroll-1 loop serialized its
// dependent atomic chain across iterations).
// ---------------------------------------------------------------------------
#define REP4(F) F(0) F(1) F(2) F(3)

__global__ void __launch_bounds__(512, 1)
gemm_fill_kernel(const float* __restrict__ ent,
                 const __bf16* __restrict__ WTh, const __bf16* __restrict__ WTl,
                 const float* __restrict__ W_S_b,
                 __bf16* __restrict__ EEb, float* __restrict__ ent_S,
                 const int* __restrict__ src, const int* __restrict__ dst,
                 const int* __restrict__ et, int* __restrict__ counts,
                 int* __restrict__ sp) {
    __shared__ __bf16 LBh[16 * 64 * 8];  // 16 KB
    __shared__ __bf16 LBl[16 * 64 * 8];  // 16 KB

    if (blockIdx.x >= NBLK_G) {
        // ================= FILL role =================
        const int fb = blockIdx.x - NBLK_G;
        const int r = blockIdx.x & 7;  // XCD heuristic (round-robin dispatch)
        const int rlo = r * NODES_PER_XCD;

#define FILL_CHUNK(c)                                                          \
        {                                                                      \
            const int e = (c) * 512 + (int)threadIdx.x;                        \
            if (e < N_EDGES) {                                                 \
                const int d = dst[e];                                          \
                if ((unsigned)(d - rlo) < (unsigned)NODES_PER_XCD) {           \
                    const int t = et[e];                                       \
                    const int row = src[e] + ((t < NUM_REL) ? 0 : N_NODES);    \
                    const int pos = atomicAdd(&counts[d], 1);                  \
                    if (pos < CAP) sp[(d << 6) + pos] = row | (t << 17);       \
                }                                                              \
            }                                                                  \
        }

#pragma unroll 1
        for (int c0 = fb >> 3; c0 < NCHUNK5; c0 += 256) {
            FILL_CHUNK(c0)
            const int c1 = c0 + 128;
            if (c1 < NCHUNK5) FILL_CHUNK(c1)
        }
#undef FILL_CHUNK
        return;
    }

    // ================= GEMM role =================
    const int tid = threadIdx.x;
    const int wv = tid >> 6;              // 0..7
    const int rg = blockIdx.x * 8 + wv;
    const bool valid = (rg < NROWG);
    const int rgc = valid ? rg : (NROWG - 1);
    const int l = tid & 63;
    const int r16 = l & 15;
    const int kg = l >> 4;

    const float* __restrict__ aptr = ent + (size_t)(rgc * 16 + r16) * DIM + kg * 8;
#define ADECL(ks)                                                              \
    bf16x8 ah##ks, al##ks;                                                     \
    {                                                                          \
        const float4 v0 = *(const float4*)(aptr + (ks) * 32);                  \
        const float4 v1 = *(const float4*)(aptr + (ks) * 32 + 4);              \
        const float xs[8] = {v0.x, v0.y, v0.z, v0.w, v1.x, v1.y, v1.z, v1.w};  \
        _Pragma("unroll") for (int i = 0; i < 8; ++i) {                        \
            const __bf16 h = (__bf16)xs[i];                                    \
            ah##ks[i] = h;                                                     \
            al##ks[i] = (__bf16)(xs[i] - (float)h);                            \
        }                                                                      \
    }
    REP4(ADECL)
#undef ADECL

    const int orow = rgc * 16 + kg * 4;

#pragma unroll 1
    for (int cb = 0; cb < 6; ++cb) {
        __syncthreads();
#pragma unroll
        for (int i = 0; i < 2; ++i) {
            const int g = i * 512 + tid;     // 0..1023
            const int sks = g >> 6;          // 0..15
            const int ls = g & 63;
            const int s = sks >> 2;
            const int ks = sks & 3;
            const size_t soff =
                (size_t)(cb * 64 + s * 16 + (ls & 15)) * DIM + ks * 32 + (ls >> 4) * 8;
            *(bf16x8*)(&LBh[g * 8]) = *(const bf16x8*)(WTh + soff);
            *(bf16x8*)(&LBl[g * 8]) = *(const bf16x8*)(WTl + soff);
        }
        __syncthreads();

        f32x4 p0 = {0.f, 0.f, 0.f, 0.f}, q0 = {0.f, 0.f, 0.f, 0.f};
        f32x4 p1 = {0.f, 0.f, 0.f, 0.f}, q1 = {0.f, 0.f, 0.f, 0.f};
        f32x4 p2 = {0.f, 0.f, 0.f, 0.f}, q2 = {0.f, 0.f, 0.f, 0.f};
        f32x4 p3 = {0.f, 0.f, 0.f, 0.f}, q3 = {0.f, 0.f, 0.f, 0.f};

#define KS(ks)                                                                 \
    {                                                                          \
        const bf16x8 bh0 = *(const bf16x8*)(&LBh[((0 * 4 + (ks)) * 64 + l) * 8]); \
        const bf16x8 bh1 = *(const bf16x8*)(&LBh[((1 * 4 + (ks)) * 64 + l) * 8]); \
        const bf16x8 bh2 = *(const bf16x8*)(&LBh[((2 * 4 + (ks)) * 64 + l) * 8]); \
        const bf16x8 bh3 = *(const bf16x8*)(&LBh[((3 * 4 + (ks)) * 64 + l) * 8]); \
        const bf16x8 bl0 = *(const bf16x8*)(&LBl[((0 * 4 + (ks)) * 64 + l) * 8]); \
        const bf16x8 bl1 = *(const bf16x8*)(&LBl[((1 * 4 + (ks)) * 64 + l) * 8]); \
        const bf16x8 bl2 = *(const bf16x8*)(&LBl[((2 * 4 + (ks)) * 64 + l) * 8]); \
        const bf16x8 bl3 = *(const bf16x8*)(&LBl[((3 * 4 + (ks)) * 64 + l) * 8]); \
        p0 = __builtin_amdgcn_mfma_f32_16x16x32_bf16(ah##ks, bh0, p0, 0, 0, 0); \
        p1 = __builtin_amdgcn_mfma_f32_16x16x32_bf16(ah##ks, bh1, p1, 0, 0, 0); \
        p2 = __builtin_amdgcn_mfma_f32_16x16x32_bf16(ah##ks, bh2, p2, 0, 0, 0); \
        p3 = __builtin_amdgcn_mfma_f32_16x16x32_bf16(ah##ks, bh3, p3, 0, 0, 0); \
        q0 = __builtin_amdgcn_mfma_f32_16x16x32_bf16(al##ks, bh0, q0, 0, 0, 0); \
        q1 = __builtin_amdgcn_mfma_f32_16x16x32_bf16(al##ks, bh1, q1, 0, 0, 0); \
        q2 = __builtin_amdgcn_mfma_f32_16x16x32_bf16(al##ks, bh2, q2, 0, 0, 0); \
        q3 = __builtin_amdgcn_mfma_f32_16x16x32_bf16(al##ks, bh3, q3, 0, 0, 0); \
        q0 = __builtin_amdgcn_mfma_f32_16x16x32_bf16(ah##ks, bl0, q0, 0, 0, 0); \
        q1 = __builtin_amdgcn_mfma_f32_16x16x32_bf16(ah##ks, bl1, q1, 0, 0, 0); \
        q2 = __builtin_amdgcn_mfma_f32_16x16x32_bf16(ah##ks, bl2, q2, 0, 0, 0); \
        q3 = __builtin_amdgcn_mfma_f32_16x16x32_bf16(ah##ks, bl3, q3, 0, 0, 0); \
    }
        REP4(KS)
#undef KS

        if (valid) {
            const int colb = (cb & 1) * 64;
            if (cb < 4) {
                __bf16* __restrict__ obb =
                    EEb + ((cb < 2) ? 0 : (size_t)N_NODES * DIM);
#define ST(s, P, Q)                                                            \
                {                                                              \
                    const int col = colb + (s) * 16 + r16;                     \
                    const f32x4 a = P + Q;                                     \
                    obb[(size_t)(orow + 0) * DIM + col] = (__bf16)a[0];        \
                    obb[(size_t)(orow + 1) * DIM + col] = (__bf16)a[1];        \
                    obb[(size_t)(orow + 2) * DIM + col] = (__bf16)a[2];        \
                    obb[(size_t)(orow + 3) * DIM + col] = (__bf16)a[3];        \
                }
                ST(0, p0, q0) ST(1, p1, q1) ST(2, p2, q2) ST(3, p3, q3)
#undef ST
            } else {
#define ST(s, P, Q)                                                            \
                {                                                              \
                    const int col = colb + (s) * 16 + r16;                     \
                    const float bs = W_S_b[col];                               \
                    const f32x4 a = P + Q;                                     \
                    ent_S[(size_t)(orow + 0) * DIM + col] = a[0] + bs;         \
                    ent_S[(size_t)(orow + 1) * DIM + col] = a[1] + bs;         \
                    ent_S[(size_t)(orow + 2) * DIM + col] = a[2] + bs;         \
                    ent_S[(size_t)(orow + 3) * DIM + col] = a[3] + bs;         \
                }
                ST(0, p0, q0) ST(1, p1, q1) ST(2, p2, q2) ST(3, p3, q3)
#undef ST
            }
        }
    }
}

// ---------------------------------------------------------------------------
// Dispatch 3: gather-reduce (unchanged).
// ---------------------------------------------------------------------------
__global__ void __launch_bounds__(256)
gather_kernel(const int* __restrict__ counts, const int* __restrict__ sp,
              const __bf16* __restrict__ EEb, const __bf16* __restrict__ Rb,
              const float* __restrict__ ent_S, float* __restrict__ out_ent) {
    const int node = blockIdx.x * 4 + (threadIdx.x >> 6);
    if (node >= N_NODES) return;
    const int l = threadIdx.x & 63;
    const int q = l >> 4;
    const int m = l & 15;

    const int cntT = counts[node];
    const int cnt = min(cntT, CAP);

    float a0 = 0.f, a1 = 0.f, a2 = 0.f, a3 = 0.f;
    float a4 = 0.f, a5 = 0.f, a6 = 0.f, a7 = 0.f;
    const char* __restrict__ Eb = (const char*)EEb + 16 * m;
    const char* __restrict__ Rp = (const char*)Rb + 16 * m;

    const int myp = (l < cnt) ? sp[(node << 6) + l] : ZPAY;
#pragma unroll 2
    for (int i = 0; i < cnt; i += 4) {
        const int p = __shfl(myp, i + q);
        const unsigned eoff = (unsigned)(p & 0x1FFFF) << 8;
        const unsigned roff = ((unsigned)p >> 17) << 8;
        const uint4 ev = *(const uint4*)(Eb + eoff);
        const uint4 rv = *(const uint4*)(Rp + roff);
        a0 += __uint_as_float(ev.x << 16) + __uint_as_float(rv.x << 16);
        a1 += __uint_as_float(ev.x & 0xffff0000u) +
              __uint_as_float(rv.x & 0xffff0000u);
        a2 += __uint_as_float(ev.y << 16) + __uint_as_float(rv.y << 16);
        a3 += __uint_as_float(ev.y & 0xffff0000u) +
              __uint_as_float(rv.y & 0xffff0000u);
        a4 += __uint_as_float(ev.z << 16) + __uint_as_float(rv.z << 16);
        a5 += __uint_as_float(ev.z & 0xffff0000u) +
              __uint_as_float(rv.z & 0xffff0000u);
        a6 += __uint_as_float(ev.w << 16) + __uint_as_float(rv.w << 16);
        a7 += __uint_as_float(ev.w & 0xffff0000u) +
              __uint_as_float(rv.w & 0xffff0000u);
    }

#define RED(A) A += __shfl_xor(A, 16); A += __shfl_xor(A, 32);
    RED(a0) RED(a1) RED(a2) RED(a3) RED(a4) RED(a5) RED(a6) RED(a7)
#undef RED

    if (l < 16) {
        const float inv = 1.0f / fmaxf((float)cntT, 1.0f);
        const float* sp_ = ent_S + (size_t)node * DIM + 8 * m;
        const float4 s0 = *(const float4*)(sp_);
        const float4 s1 = *(const float4*)(sp_ + 4);
        float4 o0, o1;
        o0.x = s0.x + a0 * inv;
        o0.y = s0.y + a1 * inv;
        o0.z = s0.z + a2 * inv;
        o0.w = s0.w + a3 * inv;
        o1.x = s1.x + a4 * inv;
        o1.y = s1.y + a5 * inv;
        o1.z = s1.z + a6 * inv;
        o1.w = s1.w + a7 * inv;
        float* op = out_ent + (size_t)node * DIM + 8 * m;
        *(float4*)(op) = o0;
        *(float4*)(op + 4) = o1;
    }
}

extern "C" void kernel_launch(void* const* d_in, const int* in_sizes, int n_in,
                              void* d_out, int out_size, void* d_ws, size_t ws_size,
                              hipStream_t stream) {
    const int* src = (const int*)d_in[0];
    const int* dst = (const int*)d_in[1];
    const int* et = (const int*)d_in[2];
    const float* ent_emb = (const float*)d_in[3];
    const float* rel_emb = (const float*)d_in[4];
    const float* W_O_w = (const float*)d_in[5];
    const float* W_O_b = (const float*)d_in[6];
    const float* W_I_w = (const float*)d_in[7];
    const float* W_I_b = (const float*)d_in[8];
    const float* W_S_w = (const float*)d_in[9];
    const float* W_S_b = (const float*)d_in[10];
    const float* W_R_w = (const float*)d_in[11];
    const float* W_R_b = (const float*)d_in[12];

    float* out_ent = (float*)d_out;                    // [50000*128]
    float* out_rel = out_ent + (size_t)N_NODES * DIM;  // [400*128]

    // Workspace layout (floats):
    // ent_S | EEb(bf16, 100001 rows) | Rb(bf16, 401 rows) | WTh | WTl |
    // counts(50000 int) | sp(50000*64 int)
    float* wsf = (float*)d_ws;
    float* ent_S = wsf;
    wsf += (size_t)N_NODES * DIM;
    __bf16* EEb = (__bf16*)wsf;
    wsf += ((size_t)(2 * N_NODES + 1) * DIM + 1) / 2;
    __bf16* Rb = (__bf16*)wsf;
    wsf += (size_t)(NREL2 + 1) * DIM / 2;
    __bf16* WTh = (__bf16*)wsf;
    wsf += 384 * DIM / 2;
    __bf16* WTl = (__bf16*)wsf;
    wsf += 384 * DIM / 2;
    int* counts = (int*)wsf;
    int* sp = counts + N_NODES;
    // total ~65 MB

    prep_rel_kernel<<<NREL2 / 2 + 196, 256, 0, stream>>>(
        rel_emb, W_O_w, W_O_b, W_I_w, W_I_b, W_R_w, W_R_b, W_S_w,
        WTh, WTl, counts, EEb, Rb, out_rel);

    gemm_fill_kernel<<<NBLK_G + FILL_NB, 512, 0, stream>>>(
        ent_emb, WTh, WTl, W_S_b, EEb, ent_S, src, dst, et, counts, sp);

    gather_kernel<<<(N_NODES + 3) / 4, 256, 0, stream>>>(counts, sp, EEb, Rb,
                                                         ent_S, out_ent);
}